// Round 3
// baseline (895.388 us; speedup 1.0000x reference)
//
#include <hip/hip_runtime.h>

typedef unsigned short u16;
typedef short bf16x8 __attribute__((ext_vector_type(8)));
typedef float f32x4 __attribute__((ext_vector_type(4)));

#define MFMA16(a,b,c) __builtin_amdgcn_mfma_f32_16x16x32_bf16((a),(b),(c),0,0,0)
#define NEGHUGE (-1.0e30f)

__device__ __forceinline__ float bf2f(u16 u){
  union { unsigned int i; float f; } v; v.i = ((unsigned int)u)<<16; return v.f;
}
__device__ __forceinline__ u16 f2b(float f){
  union { float f; unsigned int i; } v; v.f = f;
  unsigned int r = v.i + 0x7FFFu + ((v.i>>16)&1u);
  return (u16)(r>>16);
}

union BfPack { u16 h[8]; bf16x8 v; uint4 u; };

__device__ __forceinline__ bf16x8 pack8(const float* __restrict__ p){
  float4 a = *(const float4*)p;
  float4 b = *(const float4*)(p + 4);
  BfPack r;
  r.h[0]=f2b(a.x); r.h[1]=f2b(a.y); r.h[2]=f2b(a.z); r.h[3]=f2b(a.w);
  r.h[4]=f2b(b.x); r.h[5]=f2b(b.y); r.h[6]=f2b(b.z); r.h[7]=f2b(b.w);
  return r.v;
}

// LDS layout: all strides keep 16B alignment for ds_read_b128 fragment loads.
struct __align__(16) SmemA {
  u16 xc[64][104];    // x tile (bf16), K-chunk of 96 (+8 pad); rows 49..63 zeroed
  u16 Q[2][64][40];   // per-head Q; rows 49..63 zeroed
  u16 K[2][64][40];   // per-head K; rows 49..63 zeroed
  u16 Vt[2][32][72];  // V transposed [d][pos]; pos 49..63 zeroed
  u16 P[2][64][72];   // softmax probs, A-operand layout for PV
  float relb[2][169]; // rel-pos bias column per head
};

__global__ __launch_bounds__(256) void k_qkv_attn(
    const float* __restrict__ x, const float* __restrict__ wqkv,
    const float* __restrict__ relt, u16* __restrict__ attn)
{
  __shared__ SmemA S;
  const int tid = threadIdx.x;
  const int wv = tid >> 6, lane = tid & 63, quad = lane >> 4, l16 = lane & 15;
  const int blk = (int)blockIdx.x;
  const int b = blk >> 6, win = blk & 63, hb = win >> 3, wb = win & 7;

  // Zero all LDS cells any MFMA fragment can read that compute doesn't overwrite.
  for (int i = tid; i < 15*104; i += 256) S.xc[49 + i/104][i%104] = 0;
  for (int i = tid; i < 2*15*40; i += 256) {
    int hd = i / 600, r = i % 600;
    S.Q[hd][49 + r/40][r%40] = 0;
  }
  for (int i = tid; i < 2*15*40; i += 256) {
    int hd = i / 600, r = i % 600;
    S.K[hd][49 + r/40][r%40] = 0;
  }
  for (int i = tid; i < 2*32*15; i += 256) {
    int hd = i / 480, r = i % 480;
    S.Vt[hd][r/15][49 + r%15] = 0;
  }
  __syncthreads();

  for (int g = 0; g < 6; ++g) {
    const int h0 = g * 2;
    f32x4 acc[3][4];
    #pragma unroll
    for (int a = 0; a < 3; ++a)
      #pragma unroll
      for (int m = 0; m < 4; ++m) acc[a][m] = f32x4{0.f,0.f,0.f,0.f};

    // ---- QKV GEMM over K=384 in 4 chunks of 96 ----
    for (int c = 0; c < 4; ++c) {
      for (int u = tid; u < 49*12; u += 256) {
        int row = u / 12, part = u % 12;
        int py = row / 7, px = row % 7;
        int sh = hb*7 + py + 3; if (sh >= 56) sh -= 56;   // shifted -> original
        int sw = wb*7 + px + 3; if (sw >= 56) sw -= 56;
        const float* src = x + (((b*56 + sh)*56 + sw)*384 + c*96 + part*8);
        BfPack pk; pk.v = pack8(src);
        *(uint4*)(&S.xc[row][part*8]) = pk.u;
      }
      if (c == 0) {
        for (int i = tid; i < 338; i += 256)
          S.relb[i/169][i%169] = relt[(i%169)*12 + h0 + i/169];
      }
      __syncthreads();
      #pragma unroll
      for (int ks = 0; ks < 3; ++ks) {
        bf16x8 af[4];
        #pragma unroll
        for (int mt = 0; mt < 4; ++mt)
          af[mt] = *(const bf16x8*)(&S.xc[mt*16 + l16][ks*32 + quad*8]);
        #pragma unroll
        for (int jj = 0; jj < 3; ++jj) {
          const int j = wv + jj*4;                 // 12 jobs over 4 waves
          const int t = j >> 2, sub = j & 3, hd = sub >> 1, nch = sub & 1;
          const int wrow = t*384 + (h0 + hd)*32 + nch*16 + l16;
          bf16x8 bfr = pack8(wqkv + (size_t)wrow*384 + c*96 + ks*32 + quad*8);
          #pragma unroll
          for (int mt = 0; mt < 4; ++mt)
            acc[jj][mt] = MFMA16(af[mt], bfr, acc[jj][mt]);
        }
      }
      __syncthreads();
    }

    // ---- store Q/K/V to LDS (C-layout: row=quad*4+r, col=l16) ----
    #pragma unroll
    for (int jj = 0; jj < 3; ++jj) {
      const int j = wv + jj*4;
      const int t = j >> 2, sub = j & 3, hd = sub >> 1, nch = sub & 1;
      #pragma unroll
      for (int mt = 0; mt < 4; ++mt)
        #pragma unroll
        for (int r = 0; r < 4; ++r) {
          int row = mt*16 + quad*4 + r;
          if (row < 49) {
            float v = acc[jj][mt][r];
            int col = nch*16 + l16;
            if (t == 0)      S.Q[hd][row][col] = f2b(v);
            else if (t == 1) S.K[hd][row][col] = f2b(v);
            else             S.Vt[hd][col][row] = f2b(v);
          }
        }
    }
    __syncthreads();

    // ---- attention: wave -> (head = wv>>1, q-half = wv&1) ----
    const int hd = wv >> 1, half = wv & 1, head = h0 + hd;
    f32x4 sc[2][4];
    #pragma unroll
    for (int mtl = 0; mtl < 2; ++mtl) {
      const int mt = half*2 + mtl;
      bf16x8 aq = *(const bf16x8*)(&S.Q[hd][mt*16 + l16][quad*8]);
      #pragma unroll
      for (int nch = 0; nch < 4; ++nch) {
        bf16x8 bk = *(const bf16x8*)(&S.K[hd][nch*16 + l16][quad*8]);
        f32x4 z = {0.f,0.f,0.f,0.f};
        sc[mtl][nch] = MFMA16(aq, bk, z);
      }
    }
    #pragma unroll
    for (int mtl = 0; mtl < 2; ++mtl) {
      const int mt = half*2 + mtl;
      #pragma unroll
      for (int r = 0; r < 4; ++r) {
        const int q = mt*16 + quad*4 + r;
        const int qy = q / 7, qx = q - qy*7;
        #pragma unroll
        for (int nch = 0; nch < 4; ++nch) {
          const int key = nch*16 + l16;
          float s = sc[mtl][nch][r] * 0.17677669529663687f;  // 1/sqrt(32) post-MFMA
          if (key < 49 && q < 49) {
            const int ky = key / 7, kx = key - ky*7;
            s += S.relb[hd][(ky - qy + 6)*13 + (kx - qx + 6)];
            // shifted-window mask: only last row of windows, UL pattern
            if (hb == 7 && ((qy >= 4) != (ky >= 4))) s = NEGHUGE;
          } else {
            s = NEGHUGE;   // padded keys / padded rows
          }
          sc[mtl][nch][r] = s;
        }
        // row softmax: reduce across 4 nch regs + 16 lanes of this quad
        float mx = fmaxf(fmaxf(sc[mtl][0][r], sc[mtl][1][r]),
                         fmaxf(sc[mtl][2][r], sc[mtl][3][r]));
        mx = fmaxf(mx, __shfl_xor(mx, 1));
        mx = fmaxf(mx, __shfl_xor(mx, 2));
        mx = fmaxf(mx, __shfl_xor(mx, 4));
        mx = fmaxf(mx, __shfl_xor(mx, 8));
        float sum = 0.f;
        #pragma unroll
        for (int nch = 0; nch < 4; ++nch) {
          float p = exp2f((sc[mtl][nch][r] - mx) * 1.4426950408889634f);
          sc[mtl][nch][r] = p;
          sum += p;
        }
        sum += __shfl_xor(sum, 1);
        sum += __shfl_xor(sum, 2);
        sum += __shfl_xor(sum, 4);
        sum += __shfl_xor(sum, 8);
        const float rinv = 1.0f / sum;
        #pragma unroll
        for (int nch = 0; nch < 4; ++nch)
          S.P[hd][q][nch*16 + l16] = f2b(sc[mtl][nch][r] * rinv);
      }
    }
    __syncthreads();   // P fully written before PV fragment reads

    // PV: out[q][d] = sum_k P[q][k] * V[k][d]; B^T = Vt
    #pragma unroll
    for (int mtl = 0; mtl < 2; ++mtl) {
      const int mt = half*2 + mtl;
      bf16x8 ap0 = *(const bf16x8*)(&S.P[hd][mt*16 + l16][quad*8]);
      bf16x8 ap1 = *(const bf16x8*)(&S.P[hd][mt*16 + l16][32 + quad*8]);
      #pragma unroll
      for (int n2 = 0; n2 < 2; ++n2) {
        bf16x8 bv0 = *(const bf16x8*)(&S.Vt[hd][n2*16 + l16][quad*8]);
        bf16x8 bv1 = *(const bf16x8*)(&S.Vt[hd][n2*16 + l16][32 + quad*8]);
        f32x4 o = {0.f,0.f,0.f,0.f};
        o = MFMA16(ap0, bv0, o);
        o = MFMA16(ap1, bv1, o);
        #pragma unroll
        for (int r = 0; r < 4; ++r) {
          int q = mt*16 + quad*4 + r;
          if (q < 49) {
            int py = q / 7, px = q - py*7;
            int hh = hb*7 + py, ww = wb*7 + px;
            attn[(((b*56 + hh)*56 + ww)*384) + head*32 + n2*16 + l16] = f2b(o[r]);
          }
        }
      }
    }
    __syncthreads();  // protect Q/K/Vt/P/relb before next group overwrites
  }
}

// out = attn @ w_out^T + b_out (float out), written with inverse roll(+3,+3)
__global__ __launch_bounds__(256) void k_proj(
    const u16* __restrict__ attn, const float* __restrict__ wout,
    const float* __restrict__ bout, float* __restrict__ out)
{
  const int tid = threadIdx.x;
  const int wv = tid >> 6, lane = tid & 63, quad = lane >> 4, l16 = lane & 15;
  const int wid = (int)blockIdx.x * 4 + wv;     // 9408 waves
  const int mt2 = wid / 6, nb = wid % 6;
  const int m0 = mt2 * 32, n0 = nb * 64;

  f32x4 acc[2][4];
  #pragma unroll
  for (int h2 = 0; h2 < 2; ++h2)
    #pragma unroll
    for (int j = 0; j < 4; ++j) acc[h2][j] = f32x4{0.f,0.f,0.f,0.f};

  for (int k = 0; k < 12; ++k) {
    bf16x8 a0 = *(const bf16x8*)(&attn[(size_t)(m0 + l16)*384 + k*32 + quad*8]);
    bf16x8 a1 = *(const bf16x8*)(&attn[(size_t)(m0 + 16 + l16)*384 + k*32 + quad*8]);
    #pragma unroll
    for (int j = 0; j < 4; ++j) {
      bf16x8 bfr = pack8(wout + (size_t)(n0 + j*16 + l16)*384 + k*32 + quad*8);
      acc[0][j] = MFMA16(a0, bfr, acc[0][j]);
      acc[1][j] = MFMA16(a1, bfr, acc[1][j]);
    }
  }

  #pragma unroll
  for (int j = 0; j < 4; ++j) {
    const int col = n0 + j*16 + l16;
    const float bias = bout[col];
    #pragma unroll
    for (int h2 = 0; h2 < 2; ++h2)
      #pragma unroll
      for (int r = 0; r < 4; ++r) {
        int m = m0 + h2*16 + quad*4 + r;
        int w = m % 56; int t = m / 56; int h = t % 56; int bb = t / 56;
        int h_ = h + 3; if (h_ >= 56) h_ -= 56;
        int w_ = w + 3; if (w_ >= 56) w_ -= 56;
        out[((size_t)(bb*56 + h_)*56 + w_)*384 + col] = acc[h2][j][r] + bias;
      }
  }
}

extern "C" void kernel_launch(void* const* d_in, const int* in_sizes, int n_in,
                              void* d_out, int out_size, void* d_ws, size_t ws_size,
                              hipStream_t stream) {
  const float* x    = (const float*)d_in[0];
  const float* wqkv = (const float*)d_in[1];
  const float* wout = (const float*)d_in[2];
  const float* bout = (const float*)d_in[3];
  const float* relt = (const float*)d_in[4];
  u16* attn = (u16*)d_ws;               // 16*56*56*384 bf16 = 38.5 MB scratch
  float* outp = (float*)d_out;

  k_qkv_attn<<<1024, 256, 0, stream>>>(x, wqkv, relt, attn);
  k_proj<<<2352, 256, 0, stream>>>(attn, wout, bout, outp);
}

// Round 4
// 455.444 us; speedup vs baseline: 1.9660x; 1.9660x over previous
//
#include <hip/hip_runtime.h>

typedef unsigned short u16;
typedef short bf16x8 __attribute__((ext_vector_type(8)));
typedef float f32x4 __attribute__((ext_vector_type(4)));

#define MFMA16(a,b,c) __builtin_amdgcn_mfma_f32_16x16x32_bf16((a),(b),(c),0,0,0)
#define NEGHUGE (-1.0e30f)

__device__ __forceinline__ u16 f2b(float f){
  union { float f; unsigned int i; } v; v.f = f;
  unsigned int r = v.i + 0x7FFFu + ((v.i>>16)&1u);
  return (u16)(r>>16);
}

// ---------------- kernel 1: f32 -> bf16 conversion of x, w_qkv, w_out ----------
// group counts (float4 groups): x 4816896, wqkv 110592, wout 36864  => 4964352
__global__ __launch_bounds__(256) void k_convert(
    const float* __restrict__ x, const float* __restrict__ wqkv,
    const float* __restrict__ wout,
    u16* __restrict__ xbf, u16* __restrict__ wqkvb, u16* __restrict__ woutb)
{
  int idx = (int)blockIdx.x * 256 + threadIdx.x;
  const float* src; u16* dst; int off;
  if (idx < 4816896)            { src = x;    dst = xbf;    off = idx; }
  else if (idx < 4816896+110592){ src = wqkv; dst = wqkvb;  off = idx - 4816896; }
  else                          { src = wout; dst = woutb;  off = idx - 4927488; }
  float4 f = ((const float4*)src)[off];
  union { u16 h[4]; uint2 u; } p;
  p.h[0]=f2b(f.x); p.h[1]=f2b(f.y); p.h[2]=f2b(f.z); p.h[3]=f2b(f.w);
  ((uint2*)dst)[off] = p.u;
}

// ---------------- kernel 2: QKV GEMM, epilogue scatters to shifted coords -----
// qkvs[((b*56+hs)*56+ws)*1152 + n], n = {q|k|v}*384 + head*32 + d
__global__ __launch_bounds__(256) void k_qkv(
    const u16* __restrict__ xbf, const u16* __restrict__ wqkvb,
    u16* __restrict__ qkvs)
{
  const int tid = threadIdx.x;
  const int wv = tid >> 6, lane = tid & 63, quad = lane >> 4, l16 = lane & 15;
  const int wid = (int)blockIdx.x * 4 + wv;        // 14112 waves
  const int m0 = (wid / 18) * 64, n0 = (wid % 18) * 64;

  f32x4 acc[4][4];
  #pragma unroll
  for (int mi = 0; mi < 4; ++mi)
    #pragma unroll
    for (int j = 0; j < 4; ++j) acc[mi][j] = f32x4{0.f,0.f,0.f,0.f};

  for (int k = 0; k < 12; ++k) {
    bf16x8 a[4], bb[4];
    #pragma unroll
    for (int mi = 0; mi < 4; ++mi)
      a[mi] = *(const bf16x8*)(&xbf[(size_t)(m0 + mi*16 + l16)*384 + k*32 + quad*8]);
    #pragma unroll
    for (int j = 0; j < 4; ++j)
      bb[j] = *(const bf16x8*)(&wqkvb[(size_t)(n0 + j*16 + l16)*384 + k*32 + quad*8]);
    #pragma unroll
    for (int mi = 0; mi < 4; ++mi)
      #pragma unroll
      for (int j = 0; j < 4; ++j)
        acc[mi][j] = MFMA16(a[mi], bb[j], acc[mi][j]);
  }

  #pragma unroll
  for (int mi = 0; mi < 4; ++mi)
    #pragma unroll
    for (int r = 0; r < 4; ++r) {
      const int m = m0 + mi*16 + quad*4 + r;
      const int b = m / 3136, rm = m - b*3136, h = rm / 56, w = rm - h*56;
      int hs = h + 53; if (hs >= 56) hs -= 56;     // shifted coords (roll -3)
      int ws_ = w + 53; if (ws_ >= 56) ws_ -= 56;
      u16* dst = qkvs + (size_t)((b*56 + hs)*56 + ws_)*1152;
      #pragma unroll
      for (int j = 0; j < 4; ++j)
        dst[n0 + j*16 + l16] = f2b(acc[mi][j][r]);
    }
}

// ---------------- kernel 3: windowed attention, 1 wave per (window, head) -----
struct __align__(16) SmemT {
  u16 Vt[4][32][72];    // per-wave V^T [d][pos]; pos 49..63 zeroed
  u16 P[4][64][72];     // per-wave softmax probs
  float relb[4][169];   // per-wave rel-pos table column
};

__global__ __launch_bounds__(256) void k_attn(
    const u16* __restrict__ qkvs, const float* __restrict__ relt,
    u16* __restrict__ attnb)
{
  __shared__ SmemT S;
  const int tid = threadIdx.x;
  const int wv = tid >> 6, lane = tid & 63, quad = lane >> 4, l16 = lane & 15;
  const int blk = (int)blockIdx.x;                 // 3072 blocks
  const int b = blk / 192, r0 = blk % 192, win = r0 / 3, hg = r0 % 3;
  const int hb = win >> 3, wb = win & 7, head = hg*4 + wv;

  for (int i = lane; i < 169; i += 64) S.relb[wv][i] = relt[i*12 + head];

  // stage V^T: lane = pos
  {
    const int pos = lane;
    u16 vh[32];
    if (pos < 49) {
      int py = pos / 7, px = pos - py*7;
      const uint4* src = (const uint4*)(qkvs +
          (size_t)((b*56 + hb*7+py)*56 + wb*7+px)*1152 + 768 + head*32);
      #pragma unroll
      for (int t = 0; t < 4; ++t) *(uint4*)(&vh[t*8]) = src[t];
    } else {
      #pragma unroll
      for (int t = 0; t < 4; ++t) *(uint4*)(&vh[t*8]) = uint4{0,0,0,0};
    }
    #pragma unroll
    for (int d = 0; d < 32; ++d) S.Vt[wv][d][pos] = vh[d];
  }

  // Q / K fragments straight from global (A: m=pos, B: n=pos; k = quad*8..)
  bf16x8 aq[4], bk[4];
  #pragma unroll
  for (int mt = 0; mt < 4; ++mt) {
    int pos = mt*16 + l16; if (pos > 48) pos = 48;   // clamp; masked later
    int py = pos / 7, px = pos - py*7;
    const u16* src = qkvs + (size_t)((b*56 + hb*7+py)*56 + wb*7+px)*1152
                   + head*32 + quad*8;
    aq[mt] = *(const bf16x8*)src;          // Q part (n offset 0)
    bk[mt] = *(const bf16x8*)(src + 384);  // K part
  }
  __syncthreads();

  // QK^T
  f32x4 sc[4][4];
  #pragma unroll
  for (int mt = 0; mt < 4; ++mt)
    #pragma unroll
    for (int n = 0; n < 4; ++n) {
      f32x4 z = {0.f,0.f,0.f,0.f};
      sc[mt][n] = MFMA16(aq[mt], bk[n], z);
    }

  // bias + mask + softmax (row = q, per-lane rows quad*4+r per mt)
  #pragma unroll
  for (int mt = 0; mt < 4; ++mt)
    #pragma unroll
    for (int r = 0; r < 4; ++r) {
      const int q = mt*16 + quad*4 + r;
      const int qy = q / 7, qx = q - qy*7;
      #pragma unroll
      for (int n = 0; n < 4; ++n) {
        const int key = n*16 + l16;
        float s = sc[mt][n][r] * 0.17677669529663687f;   // 1/sqrt(32)
        if (key < 49 && q < 49) {
          const int ky = key / 7, kx = key - ky*7;
          s += S.relb[wv][(ky - qy + 6)*13 + (kx - qx + 6)];
          if (hb == 7 && ((qy >= 4) != (ky >= 4))) s = NEGHUGE;  // UL mask
        } else {
          s = NEGHUGE;
        }
        sc[mt][n][r] = s;
      }
      float mx = fmaxf(fmaxf(sc[mt][0][r], sc[mt][1][r]),
                       fmaxf(sc[mt][2][r], sc[mt][3][r]));
      mx = fmaxf(mx, __shfl_xor(mx, 1));
      mx = fmaxf(mx, __shfl_xor(mx, 2));
      mx = fmaxf(mx, __shfl_xor(mx, 4));
      mx = fmaxf(mx, __shfl_xor(mx, 8));
      float sum = 0.f;
      #pragma unroll
      for (int n = 0; n < 4; ++n) {
        float p = exp2f((sc[mt][n][r] - mx) * 1.4426950408889634f);
        sc[mt][n][r] = p; sum += p;
      }
      sum += __shfl_xor(sum, 1);
      sum += __shfl_xor(sum, 2);
      sum += __shfl_xor(sum, 4);
      sum += __shfl_xor(sum, 8);
      const float rinv = 1.0f / sum;
      #pragma unroll
      for (int n = 0; n < 4; ++n)
        S.P[wv][q][n*16 + l16] = f2b(sc[mt][n][r] * rinv);
    }
  __syncthreads();

  // PV
  #pragma unroll
  for (int mt = 0; mt < 4; ++mt) {
    bf16x8 ap0 = *(const bf16x8*)(&S.P[wv][mt*16 + l16][quad*8]);
    bf16x8 ap1 = *(const bf16x8*)(&S.P[wv][mt*16 + l16][32 + quad*8]);
    #pragma unroll
    for (int n2 = 0; n2 < 2; ++n2) {
      bf16x8 bv0 = *(const bf16x8*)(&S.Vt[wv][n2*16 + l16][quad*8]);
      bf16x8 bv1 = *(const bf16x8*)(&S.Vt[wv][n2*16 + l16][32 + quad*8]);
      f32x4 o = {0.f,0.f,0.f,0.f};
      o = MFMA16(ap0, bv0, o);
      o = MFMA16(ap1, bv1, o);
      #pragma unroll
      for (int r = 0; r < 4; ++r) {
        int q = mt*16 + quad*4 + r;
        if (q < 49) {
          int py = q / 7, px = q - py*7;
          attnb[(size_t)((b*56 + hb*7+py)*56 + wb*7+px)*384
                + head*32 + n2*16 + l16] = f2b(o[r]);
        }
      }
    }
  }
}

// ---------------- kernel 4: out = attn @ w_out^T + b_out, inverse roll(+3) ---
__global__ __launch_bounds__(256) void k_proj(
    const u16* __restrict__ attnb, const u16* __restrict__ woutb,
    const float* __restrict__ bout, float* __restrict__ out)
{
  const int tid = threadIdx.x;
  const int wv = tid >> 6, lane = tid & 63, quad = lane >> 4, l16 = lane & 15;
  const int wid = (int)blockIdx.x * 4 + wv;     // 9408 waves
  const int mt2 = wid / 6, nb = wid % 6;
  const int m0 = mt2 * 32, n0 = nb * 64;

  f32x4 acc[2][4];
  #pragma unroll
  for (int h2 = 0; h2 < 2; ++h2)
    #pragma unroll
    for (int j = 0; j < 4; ++j) acc[h2][j] = f32x4{0.f,0.f,0.f,0.f};

  for (int k = 0; k < 12; ++k) {
    bf16x8 a0 = *(const bf16x8*)(&attnb[(size_t)(m0 + l16)*384 + k*32 + quad*8]);
    bf16x8 a1 = *(const bf16x8*)(&attnb[(size_t)(m0 + 16 + l16)*384 + k*32 + quad*8]);
    #pragma unroll
    for (int j = 0; j < 4; ++j) {
      bf16x8 bfr = *(const bf16x8*)(&woutb[(size_t)(n0 + j*16 + l16)*384 + k*32 + quad*8]);
      acc[0][j] = MFMA16(a0, bfr, acc[0][j]);
      acc[1][j] = MFMA16(a1, bfr, acc[1][j]);
    }
  }

  #pragma unroll
  for (int j = 0; j < 4; ++j) {
    const int col = n0 + j*16 + l16;
    const float bias = bout[col];
    #pragma unroll
    for (int h2 = 0; h2 < 2; ++h2)
      #pragma unroll
      for (int r = 0; r < 4; ++r) {
        int m = m0 + h2*16 + quad*4 + r;
        int w = m % 56; int t = m / 56; int h = t % 56; int bb = t / 56;
        int h_ = h + 3; if (h_ >= 56) h_ -= 56;
        int w_ = w + 3; if (w_ >= 56) w_ -= 56;
        out[((size_t)(bb*56 + h_)*56 + w_)*384 + col] = acc[h2][j][r] + bias;
      }
  }
}

extern "C" void kernel_launch(void* const* d_in, const int* in_sizes, int n_in,
                              void* d_out, int out_size, void* d_ws, size_t ws_size,
                              hipStream_t stream) {
  const float* x    = (const float*)d_in[0];
  const float* wqkv = (const float*)d_in[1];
  const float* wout = (const float*)d_in[2];
  const float* bout = (const float*)d_in[3];
  const float* relt = (const float*)d_in[4];

  char* ws = (char*)d_ws;
  u16* qkvs  = (u16*)(ws);                        // 115,605,504 B
  u16* wqkvb = (u16*)(ws + 115605504);            //     884,736 B
  u16* woutb = (u16*)(ws + 116490240);            //     294,912 B
  u16* xbf   = (u16*)(ws + 116785152);            //  38,535,168 B (aliased attnb)
  u16* attnb = xbf;                               // xbf dead after k_qkv
  float* outp = (float*)d_out;

  k_convert<<<19392, 256, 0, stream>>>(x, wqkv, wout, xbf, wqkvb, woutb);
  k_qkv<<<3528, 256, 0, stream>>>(xbf, wqkvb, qkvs);
  k_attn<<<3072, 256, 0, stream>>>(qkvs, relt, attnb);
  k_proj<<<2352, 256, 0, stream>>>(attnb, woutb, bout, outp);
}